// Round 9
// baseline (102.793 us; speedup 1.0000x reference)
//
#include <hip/hip_runtime.h>
#include <hip/hip_bf16.h>

#define H 256
#define Wd 256
#define H2 128

typedef unsigned short ushort_t;
typedef __attribute__((ext_vector_type(8))) short short8;
typedef __attribute__((ext_vector_type(4))) float f32x4;
typedef __attribute__((ext_vector_type(2))) float f32x2;

__device__ __forceinline__ float mishf(float v){
  if (v > 15.f) return v;
  float e = __expf(v);
  float w = e*(e+2.f);
  return v * w * __builtin_amdgcn_rcpf(w + 2.f);
}

__device__ __forceinline__ ushort_t f2bf(float f){
  unsigned int u = __float_as_uint(f);
  u += 0x7fffu + ((u >> 16) & 1u);
  return (ushort_t)(u >> 16);
}
__device__ __forceinline__ float bf2f(ushort_t h){
  return __uint_as_float(((unsigned int)h) << 16);
}
__device__ __forceinline__ unsigned packbf(float a, float b){
  return (unsigned)f2bf(a) | ((unsigned)f2bf(b) << 16);
}

// Packed fp32 FMA, weight pair in SGPRs (uniform), broadcast of lo/hi half.
#define PK_LO(acc, f, w) \
  asm("v_pk_fma_f32 %0, %1, %2, %0 op_sel_hi:[1,0,1]" \
      : "+v"(acc) : "v"(f), "s"(w))
#define PK_HI(acc, f, w) \
  asm("v_pk_fma_f32 %0, %1, %2, %0 op_sel:[0,1,0] op_sel_hi:[1,1,1]" \
      : "+v"(acc) : "v"(f), "s"(w))

// ---------------------------------------------------------------------------
// shuf layout: 8-byte pixel records  [plane = b*16 + c][i*256 + j][m0..3]
// (bf16 x4). k12r writes top rows (own plane) and bottom rows (rolled plane).
// ---------------------------------------------------------------------------

// K0: pre-pack W2 into bf16 MFMA A-fragment order.
__global__ void k0_pack(const float* __restrict__ W2, ushort_t* __restrict__ wpack)
{
  int idx = blockIdx.x*128 + threadIdx.x;   // 0..1151
  if (idx >= 1152) return;
  int lane  = idx & 63;
  int s     = (idx >> 6) % 9;
  int khalf = idx / 576;
  int n = lane & 15, g = lane >> 4;
  unsigned int w[4];
#pragma unroll
  for (int h = 0; h < 4; ++h){
    int ch0 = khalf*32 + g*8 + 2*h;
    unsigned lo = f2bf(W2[(n*64 + ch0  )*9 + s]);
    unsigned hi = f2bf(W2[(n*64 + ch0+1)*9 + s]);
    w[h] = lo | (hi << 16);
  }
  *(uint4*)(wpack + (size_t)idx*8) = make_uint4(w[0], w[1], w[2], w[3]);
}

// ---------------------------------------------------------------------------
// K12R: register-only fused conv1 top+bottom. NO LDS, NO barriers.
// Thread = 4 top px of one row (i, j0..j0+3) of one plane.
//  - x window loaded as per-lane float4 triplets (left/mid/right), rolled
//    through 3 live rows of 7 overlapping f32x2 pairs.
//  - f computed redundantly at 3x6 positions; span A/B accumulated per f-row.
//  - f_bot computed for rows 128+i -> rolled-plane store + g.
// ---------------------------------------------------------------------------
__global__ __launch_bounds__(256) void k12r(
    const float* __restrict__ x, const float* __restrict__ W1,
    const float* __restrict__ b1, const float* __restrict__ Wred,
    const float* __restrict__ bred, const float* __restrict__ Wspan,
    const float* __restrict__ bspan, ushort_t* __restrict__ shuf)
{
  int bid = blockIdx.x;             // 128 planes * 32 rowgroups
  int n   = bid >> 5;
  int rg  = bid & 31;
  int tid = threadIdx.x;
  int i   = rg*4 + (tid >> 6);      // top row 0..127
  int j0  = (tid & 63) * 4;
  const float* xp = x + (size_t)n * (H*Wd);
  bool jlo = (j0 == 0), jhi = (j0 == 252);

  f32x2 w01[9], w23[9];
  float wsp[9], bsp[9], wredr[4];
  float bredr = bred[0];
#pragma unroll
  for (int k=0;k<9;k++){
    w01[k] = f32x2{W1[k], W1[9+k]};
    w23[k] = f32x2{W1[18+k], W1[27+k]};
    wsp[k] = Wspan[k]; bsp[k] = bspan[k];
  }
#pragma unroll
  for (int m=0;m<4;m++) wredr[m] = Wred[m];
  f32x2 bp0 = f32x2{b1[0], b1[0]};
  f32x2 bp1 = f32x2{b1[1], b1[1]};
  f32x2 bp2 = f32x2{b1[2], b1[2]};
  f32x2 bp3 = f32x2{b1[3], b1[3]};

  const float4 f4z = make_float4(0.f,0.f,0.f,0.f);
  f32x2 PA[7], PB[7], PC[7];

  // Load x row -> 7 overlapping pairs P[k]=(X[2+k],X[3+k]), X = cols j0-4..j0+7
#define LROWP(row_, P_) { \
    int row__ = (row_); \
    float4 lm=f4z, mm=f4z, rm=f4z; \
    if ((unsigned)row__ < 256u){ \
      const float* rp = xp + (size_t)row__*Wd + j0; \
      mm = *(const float4*)rp; \
      if (!jlo) lm = *(const float4*)(rp-4); \
      if (!jhi) rm = *(const float4*)(rp+4); \
    } \
    P_[0] = f32x2{lm.z, lm.w}; \
    P_[1] = f32x2{lm.w, mm.x}; \
    P_[2] = f32x2{mm.x, mm.y}; \
    P_[3] = f32x2{mm.y, mm.z}; \
    P_[4] = f32x2{mm.z, mm.w}; \
    P_[5] = f32x2{mm.w, rm.x}; \
    P_[6] = f32x2{rm.x, rm.y}; \
  }

  float A[4][4], Bv[4][4];
#pragma unroll
  for (int m=0;m<4;m++)
#pragma unroll
    for (int p=0;p<4;p++){ A[m][p]=0.f; Bv[m][p]=0.f; }

  // conv1+mish at f-row (rows R0,R1,R2 = x rows fr-1,fr,fr+1), then span acc.
#define CONVSPAN(R0_, R1_, R2_, KY_) { \
    float fm[4][6]; \
    _Pragma("unroll") \
    for (int cp=0; cp<3; ++cp){ \
      f32x2 s0=bp0, s1=bp1, s2=bp2, s3=bp3; \
      _Pragma("unroll") \
      for (int kx=0; kx<3; ++kx){ \
        PK_LO(s0, R0_[2*cp+kx], w01[kx]);   PK_HI(s1, R0_[2*cp+kx], w01[kx]); \
        PK_LO(s2, R0_[2*cp+kx], w23[kx]);   PK_HI(s3, R0_[2*cp+kx], w23[kx]); \
        PK_LO(s0, R1_[2*cp+kx], w01[3+kx]); PK_HI(s1, R1_[2*cp+kx], w01[3+kx]); \
        PK_LO(s2, R1_[2*cp+kx], w23[3+kx]); PK_HI(s3, R1_[2*cp+kx], w23[3+kx]); \
        PK_LO(s0, R2_[2*cp+kx], w01[6+kx]); PK_HI(s1, R2_[2*cp+kx], w01[6+kx]); \
        PK_LO(s2, R2_[2*cp+kx], w23[6+kx]); PK_HI(s3, R2_[2*cp+kx], w23[6+kx]); \
      } \
      fm[0][2*cp]=mishf(s0.x); fm[0][2*cp+1]=mishf(s0.y); \
      fm[1][2*cp]=mishf(s1.x); fm[1][2*cp+1]=mishf(s1.y); \
      fm[2][2*cp]=mishf(s2.x); fm[2][2*cp+1]=mishf(s2.y); \
      fm[3][2*cp]=mishf(s3.x); fm[3][2*cp+1]=mishf(s3.y); \
    } \
    if (jlo){ fm[0][0]=0.f; fm[1][0]=0.f; fm[2][0]=0.f; fm[3][0]=0.f; } \
    if (jhi){ fm[0][5]=0.f; fm[1][5]=0.f; fm[2][5]=0.f; fm[3][5]=0.f; } \
    _Pragma("unroll") \
    for (int m=0;m<4;m++) \
      _Pragma("unroll") \
      for (int p=0;p<4;p++){ \
        _Pragma("unroll") \
        for (int kx=0;kx<3;kx++){ \
          A[m][p]  = fmaf(fm[m][p+kx], wsp[(KY_)*3+kx], A[m][p]); \
          Bv[m][p] = fmaf(fm[m][p+kx], bsp[(KY_)*3+kx], Bv[m][p]); \
        } \
      } \
  }

  // ---- top: 3 f-rows, rolling x rows ----
  LROWP(i-2, PA); LROWP(i-1, PB); LROWP(i, PC);
  if (i >= 1) { CONVSPAN(PA, PB, PC, 0); }        // frow i-1 (zero if < 0)
  LROWP(i+1, PA);
  { CONVSPAN(PB, PC, PA, 1); }                     // frow i (always valid)
  LROWP(i+2, PB);
  if (i <= 126) { CONVSPAN(PC, PA, PB, 2); }      // frow i+1 (zero if > 127)

  // ---- bottom: f_bot at row 128+i, cols j0..j0+3 (px-pair accumulation) ----
  LROWP(127+i, PA); LROWP(128+i, PB); LROWP(129+i, PC);  // row 256 -> zeros
  f32x2 sA0=bp0,sA1=bp1,sA2=bp2,sA3=bp3;
  f32x2 sB0=bp0,sB1=bp1,sB2=bp2,sB3=bp3;
#pragma unroll
  for (int kx=0; kx<3; ++kx){
    PK_LO(sA0, PA[1+kx], w01[kx]);   PK_HI(sA1, PA[1+kx], w01[kx]);
    PK_LO(sA2, PA[1+kx], w23[kx]);   PK_HI(sA3, PA[1+kx], w23[kx]);
    PK_LO(sB0, PA[3+kx], w01[kx]);   PK_HI(sB1, PA[3+kx], w01[kx]);
    PK_LO(sB2, PA[3+kx], w23[kx]);   PK_HI(sB3, PA[3+kx], w23[kx]);
    PK_LO(sA0, PB[1+kx], w01[3+kx]); PK_HI(sA1, PB[1+kx], w01[3+kx]);
    PK_LO(sA2, PB[1+kx], w23[3+kx]); PK_HI(sA3, PB[1+kx], w23[3+kx]);
    PK_LO(sB0, PB[3+kx], w01[3+kx]); PK_HI(sB1, PB[3+kx], w01[3+kx]);
    PK_LO(sB2, PB[3+kx], w23[3+kx]); PK_HI(sB3, PB[3+kx], w23[3+kx]);
    PK_LO(sA0, PC[1+kx], w01[6+kx]); PK_HI(sA1, PC[1+kx], w01[6+kx]);
    PK_LO(sA2, PC[1+kx], w23[6+kx]); PK_HI(sA3, PC[1+kx], w23[6+kx]);
    PK_LO(sB0, PC[3+kx], w01[6+kx]); PK_HI(sB1, PC[3+kx], w01[6+kx]);
    PK_LO(sB2, PC[3+kx], w23[6+kx]); PK_HI(sB3, PC[3+kx], w23[6+kx]);
  }
  float fb[4][4];
  fb[0][0]=mishf(sA0.x); fb[0][1]=mishf(sA0.y); fb[0][2]=mishf(sB0.x); fb[0][3]=mishf(sB0.y);
  fb[1][0]=mishf(sA1.x); fb[1][1]=mishf(sA1.y); fb[1][2]=mishf(sB1.x); fb[1][3]=mishf(sB1.y);
  fb[2][0]=mishf(sA2.x); fb[2][1]=mishf(sA2.y); fb[2][2]=mishf(sB2.x); fb[2][3]=mishf(sB2.y);
  fb[3][0]=mishf(sA3.x); fb[3][1]=mishf(sA3.y); fb[3][2]=mishf(sB3.x); fb[3][3]=mishf(sB3.y);

  int bq = n >> 4, cq = n & 15;
  int cdst = (cq + 15) & 15;
  size_t bbase = ((size_t)(bq*16 + cdst))*65536 + (size_t)(128+i)*256 + j0;
  {
    unsigned w0 = packbf(fb[0][0], fb[1][0]), w1 = packbf(fb[2][0], fb[3][0]);
    unsigned w2 = packbf(fb[0][1], fb[1][1]), w3 = packbf(fb[2][1], fb[3][1]);
    *(uint4*)(shuf + bbase*4) = make_uint4(w0,w1,w2,w3);
    unsigned w4 = packbf(fb[0][2], fb[1][2]), w5 = packbf(fb[2][2], fb[3][2]);
    unsigned w6 = packbf(fb[0][3], fb[1][3]), w7 = packbf(fb[2][3], fb[3][3]);
    *(uint4*)(shuf + (bbase+2)*4) = make_uint4(w4,w5,w6,w7);
  }
  float gv[4];
#pragma unroll
  for (int p=0;p<4;p++){
    float s = bredr;
#pragma unroll
    for (int m=0;m<4;m++) s = fmaf(fb[m][p], wredr[m], s);
    gv[p] = fmaxf(s, 0.f);
  }

  // ---- combine and store top ----
  float o[4][4];
#pragma unroll
  for (int m=0;m<4;m++)
#pragma unroll
    for (int p=0;p<4;p++)
      o[m][p] = fmaf(gv[p], A[m][p], Bv[m][p]);

  size_t pbase = ((size_t)n)*65536 + (size_t)i*256 + j0;
  {
    unsigned w0 = packbf(o[0][0], o[1][0]), w1 = packbf(o[2][0], o[3][0]);
    unsigned w2 = packbf(o[0][1], o[1][1]), w3 = packbf(o[2][1], o[3][1]);
    *(uint4*)(shuf + pbase*4) = make_uint4(w0,w1,w2,w3);
    unsigned w4 = packbf(o[0][2], o[1][2]), w5 = packbf(o[2][2], o[3][2]);
    unsigned w6 = packbf(o[0][3], o[1][3]), w7 = packbf(o[2][3], o[3][3]);
    *(uint4*)(shuf + (pbase+2)*4) = make_uint4(w4,w5,w6,w7);
  }
#undef LROWP
#undef CONVSPAN
}

// ---------------------------------------------------------------------------
// K3: conv2 via MFMA implicit GEMM, direct-from-global B fragments.
// ---------------------------------------------------------------------------
__global__ __launch_bounds__(256) void k3_conv2(
    const ushort_t* __restrict__ shuf, const ushort_t* __restrict__ wpack,
    const float* __restrict__ b2, float* __restrict__ scratch)
{
  __shared__ f32x4 mg[2][8][64];   // 16 KiB
  __shared__ float pacc[16];

  int bid0 = blockIdx.x;                     // 2048
  int bid  = (bid0 & 7)*256 + (bid0 >> 3);   // XCD-contiguous chunks
  int b   = bid >> 8;
  int t   = bid & 255;
  int rb  = t >> 3;
  int cb  = t & 7;
  int tid = threadIdx.x;
  int lane = tid & 63;
  int n = lane & 15;
  int g = lane >> 4;
  int wid = tid >> 6;
  int colhalf = wid & 1;
  int khalf   = wid >> 1;

  if (tid < 16) pacc[tid] = 0.f;

  const short8* wp = (const short8*)wpack + (size_t)khalf*576 + lane;
  short8 afr[9];
#pragma unroll
  for (int s = 0; s < 9; ++s) afr[s] = wp[s*64];

  f32x4 acc[8];
#pragma unroll
  for (int r = 0; r < 8; ++r) acc[r] = f32x4{0.f,0.f,0.f,0.f};

  int r0 = rb*8 - 1;
  int c  = cb*32 - 1 + colhalf*16 + n;
  int p0 = khalf*8 + g*2;
  const ushort_t* sp = shuf + ((size_t)(b*16 + p0))*262144;

#pragma unroll
  for (int hr = 0; hr < 10; ++hr){
    int grow = r0 + hr;
    bool rok = (unsigned)grow < 256u;
    uint2 va[3], vb[3];
#pragma unroll
    for (int kx = 0; kx < 3; ++kx){
      int gcol = c + kx;
      uint2 a = make_uint2(0u,0u), bv = make_uint2(0u,0u);
      if (rok && (unsigned)gcol < 256u){
        const ushort_t* pp = sp + (size_t)(grow*256 + gcol)*4;
        a  = *(const uint2*)pp;
        bv = *(const uint2*)(pp + 262144);
      }
      va[kx] = a; vb[kx] = bv;
    }
#pragma unroll
    for (int kx = 0; kx < 3; ++kx){
      union { uint4 u; short8 s; } cv;
      cv.u = make_uint4(va[kx].x, va[kx].y, vb[kx].x, vb[kx].y);
#pragma unroll
      for (int ky = 0; ky < 3; ++ky){
        int orow = hr - ky;
        if (orow >= 0 && orow < 8){
          acc[orow] = __builtin_amdgcn_mfma_f32_16x16x32_bf16(
              afr[ky*3+kx], cv.s, acc[orow], 0, 0, 0);
        }
      }
    }
  }

  if (khalf == 1){
#pragma unroll
    for (int r = 0; r < 8; ++r) mg[colhalf][r][lane] = acc[r];
  }
  __syncthreads();

  if (khalf == 0){
    float b2v[4];
#pragma unroll
    for (int q = 0; q < 4; ++q) b2v[q] = b2[g*4 + q];
    float po[4] = {0.f, 0.f, 0.f, 0.f};
#pragma unroll
    for (int r = 0; r < 8; ++r){
      f32x4 o = acc[r] + mg[colhalf][r][lane];
#pragma unroll
      for (int q = 0; q < 4; ++q) po[q] += mishf(o[q] + b2v[q]);
    }
#pragma unroll
    for (int q = 0; q < 4; ++q){
#pragma unroll
      for (int mk = 1; mk < 16; mk <<= 1) po[q] += __shfl_xor(po[q], mk);
    }
    if (n == 0){
#pragma unroll
      for (int q = 0; q < 4; ++q) atomicAdd(&pacc[g*4 + q], po[q]);
    }
  }
  __syncthreads();
  if (tid < 16) scratch[bid*16 + tid] = pacc[tid];
}

// K4: reduce per-block partials -> pooled mean -> ECA gate. One block per b.
__global__ void k4_gate(const float* __restrict__ scratch,
                        const float* __restrict__ Weca,
                        float* __restrict__ gate)
{
  __shared__ float rr[16][16];
  __shared__ float pool[16];
  int b = blockIdx.x;
  int t = threadIdx.x;           // 256
  int oc = t & 15, ch = t >> 4;
  float s = 0.f;
  for (int u = 0; u < 16; ++u)
    s += scratch[(size_t)(b*256 + ch*16 + u)*16 + oc];
  rr[ch][oc] = s;
  __syncthreads();
  if (t < 16){
    float tot = 0.f;
#pragma unroll
    for (int k = 0; k < 16; ++k) tot += rr[k][t];
    pool[t] = tot * (1.0f/65536.0f);
  }
  __syncthreads();
  if (t < 16){
    float pm = (t > 0)  ? pool[t-1] : 0.f;
    float p0 = pool[t];
    float pp = (t < 15) ? pool[t+1] : 0.f;
    float z = Weca[0]*pm + Weca[1]*p0 + Weca[2]*pp;
    gate[b*16 + t] = 1.f/(1.f + __expf(-z));
  }
}

// K5: out = x * gate[b,c], nontemporal stores
__global__ __launch_bounds__(256) void k5_scale(
    const f32x4* __restrict__ x4, const float* __restrict__ gate,
    f32x4* __restrict__ out4)
{
  int idx = blockIdx.x*256 + threadIdx.x;
  float g = gate[idx >> 14];
  f32x4 v = x4[idx] * g;
  __builtin_nontemporal_store(v, &out4[idx]);
}

extern "C" void kernel_launch(void* const* d_in, const int* in_sizes, int n_in,
                              void* d_out, int out_size, void* d_ws, size_t ws_size,
                              hipStream_t stream)
{
  const float* x     = (const float*)d_in[0];
  const float* W1    = (const float*)d_in[1];
  const float* b1    = (const float*)d_in[2];
  const float* Wred  = (const float*)d_in[3];
  const float* bred  = (const float*)d_in[4];
  const float* Wspan = (const float*)d_in[5];
  const float* bspan = (const float*)d_in[6];
  const float* W2    = (const float*)d_in[7];
  const float* b2    = (const float*)d_in[8];
  const float* Weca  = (const float*)d_in[9];

  ushort_t* shuf    = (ushort_t*)d_ws;                        // 64 MiB records
  float*    gate    = (float*)((char*)d_ws + 67108864);       // 512 B
  ushort_t* wpack   = (ushort_t*)((char*)d_ws + 67108864 + 1024); // 18.4 KiB
  float*    scratch = (float*)d_out;  // 2048*16 floats; overwritten by k5

  k0_pack<<<9, 128, 0, stream>>>(W2, wpack);
  k12r   <<<4096, 256, 0, stream>>>(x, W1, b1, Wred, bred, Wspan, bspan, shuf);
  k3_conv2<<<2048, 256, 0, stream>>>(shuf, wpack, b2, scratch);
  k4_gate<<<8, 256, 0, stream>>>(scratch, Weca, gate);
  k5_scale<<<8192, 256, 0, stream>>>((const f32x4*)x, gate, (f32x4*)d_out);
}

// Round 10
// 91.127 us; speedup vs baseline: 1.1280x; 1.1280x over previous
//
#include <hip/hip_runtime.h>
#include <hip/hip_bf16.h>

#define H 256
#define Wd 256
#define H2 128

typedef unsigned short ushort_t;
typedef __attribute__((ext_vector_type(8))) short short8;
typedef __attribute__((ext_vector_type(4))) float f32x4;

// guarded mish (k3: conv2 outputs can be larger; keep the clamp)
__device__ __forceinline__ float mishf(float v){
  if (v > 15.f) return v;
  float e = __expf(v);
  float w = e*(e+2.f);
  return v * w * __builtin_amdgcn_rcpf(w + 2.f);
}
// slim mish (k12h: conv1 outputs bounded |s| < ~25 -> no overflow possible)
__device__ __forceinline__ float mish_s(float v){
  float e = __expf(v);
  float w = e*(e+2.f);
  return v * w * __builtin_amdgcn_rcpf(w + 2.f);
}

__device__ __forceinline__ ushort_t f2bf(float f){
  unsigned int u = __float_as_uint(f);
  u += 0x7fffu + ((u >> 16) & 1u);
  return (ushort_t)(u >> 16);
}
__device__ __forceinline__ unsigned packbf(float a, float b){
  return (unsigned)f2bf(a) | ((unsigned)f2bf(b) << 16);
}
__device__ __forceinline__ float lo16(unsigned u){
  return __uint_as_float(u << 16);
}
__device__ __forceinline__ float hi16(unsigned u){
  return __uint_as_float(u & 0xffff0000u);
}

// ---------------------------------------------------------------------------
// shuf layout: 8-byte pixel records  [plane = b*16 + c][i*256 + j][m0..3]
// (bf16 x4). k12h writes top rows (own plane) and bottom rows (rolled plane).
// ---------------------------------------------------------------------------

// K0: pre-pack W2 into bf16 MFMA A-fragment order.
__global__ void k0_pack(const float* __restrict__ W2, ushort_t* __restrict__ wpack)
{
  int idx = blockIdx.x*128 + threadIdx.x;   // 0..1151
  if (idx >= 1152) return;
  int lane  = idx & 63;
  int s     = (idx >> 6) % 9;
  int khalf = idx / 576;
  int n = lane & 15, g = lane >> 4;
  unsigned int w[4];
#pragma unroll
  for (int h = 0; h < 4; ++h){
    int ch0 = khalf*32 + g*8 + 2*h;
    unsigned lo = f2bf(W2[(n*64 + ch0  )*9 + s]);
    unsigned hi = f2bf(W2[(n*64 + ch0+1)*9 + s]);
    w[h] = lo | (hi << 16);
  }
  *(uint4*)(wpack + (size_t)idx*8) = make_uint4(w[0], w[1], w[2], w[3]);
}

// ---------------------------------------------------------------------------
// K12H: fused conv1 top+bottom, minimal-LDS design.
//  Phase1: f_top produced ONCE per 4-px quad (306 quads/block) from direct
//          global float4 loads -> packed bf16 px-major LDS tile (8 B/px),
//          written as 2x b128. LDS row stride 560 B.
//  Phase2: f_bot in registers from global (no LDS) -> rolled-plane store + g.
//  (one barrier)
//  Phase4: span convs A,B from 12x b128 LDS reads; o = g*A + B -> top store.
// ---------------------------------------------------------------------------
#define FT_STRIDE 560   // bytes per ftl row (68 px * 8 B + pad)
__global__ __launch_bounds__(256) void k12h(
    const float* __restrict__ x, const float* __restrict__ W1,
    const float* __restrict__ b1, const float* __restrict__ Wred,
    const float* __restrict__ bred, const float* __restrict__ Wspan,
    const float* __restrict__ bspan, ushort_t* __restrict__ shuf)
{
  __shared__ __align__(16) char ftl[18*FT_STRIDE];   // ~10 KB

  int bid = blockIdx.x;             // 128 planes * 8 rowtiles * 4 coltiles
  int n   = bid >> 5;
  int t   = bid & 31;
  int itop0 = (t >> 2) * 16;
  int j0    = (t & 3) * 64;
  int tid = threadIdx.x;
  const float* xp = x + (size_t)n * (H*Wd);
  const float4 f4z = make_float4(0.f,0.f,0.f,0.f);

  float w1r[36], b1r[4], wsp[9], bsp[9], wredr[4];
  float bredr = bred[0];
#pragma unroll
  for (int k=0;k<36;k++) w1r[k] = W1[k];
#pragma unroll
  for (int m=0;m<4;m++){ b1r[m] = b1[m]; wredr[m] = Wred[m]; }
#pragma unroll
  for (int k=0;k<9;k++){ wsp[k] = Wspan[k]; bsp[k] = bspan[k]; }

  // ---- Phase 1: produce f_top tile (rows frow=itop0-1..itop0+16,
  //      slots s=0..67 <-> f-col j0-2+s), once per quad ----
#pragma unroll
  for (int pi0 = 0; pi0 < 2; ++pi0){
    int pi = tid + pi0*256;
    if (pi < 306){
      int r  = pi / 17;              // 0..17
      int q  = pi - r*17;            // 0..16
      int frow  = itop0 - 1 + r;
      int fcol0 = j0 - 2 + 4*q;      // quad covers f-cols fcol0..fcol0+3
      uint4 o0 = make_uint4(0u,0u,0u,0u), o1 = make_uint4(0u,0u,0u,0u);
      if ((unsigned)frow < 128u){
        float v[3][8];               // x cols fcol0-2 .. fcol0+5
        int cA = fcol0 - 2, cB = fcol0 + 2;
#pragma unroll
        for (int rr=0; rr<3; ++rr){
          int xr = frow - 1 + rr;    // in [-1,128] -> only low guard needed
          bool rok = (xr >= 0);
          const float* rp = xp + (size_t)xr*Wd;
          float4 a = (rok && cA >= 0)   ? *(const float4*)(rp + cA) : f4z;
          float4 b = (rok && cB <= 252) ? *(const float4*)(rp + cB) : f4z;
          v[rr][0]=a.x; v[rr][1]=a.y; v[rr][2]=a.z; v[rr][3]=a.w;
          v[rr][4]=b.x; v[rr][5]=b.y; v[rr][6]=b.z; v[rr][7]=b.w;
        }
        float s[4][4];
#pragma unroll
        for (int m=0;m<4;m++)
#pragma unroll
          for (int p=0;p<4;p++) s[m][p] = b1r[m];
#pragma unroll
        for (int ky=0;ky<3;ky++)
#pragma unroll
          for (int kx=0;kx<3;kx++){
#pragma unroll
            for (int m=0;m<4;m++){
              float wv = w1r[m*9+ky*3+kx];
#pragma unroll
              for (int p=0;p<4;p++)
                s[m][p] = fmaf(v[ky][p+1+kx], wv, s[m][p]);
            }
          }
        unsigned pw[8];
#pragma unroll
        for (int p=0;p<4;p++){
          bool ok = (unsigned)(fcol0+p) < 256u;
          pw[p*2]   = ok ? packbf(mish_s(s[0][p]), mish_s(s[1][p])) : 0u;
          pw[p*2+1] = ok ? packbf(mish_s(s[2][p]), mish_s(s[3][p])) : 0u;
        }
        o0 = make_uint4(pw[0],pw[1],pw[2],pw[3]);
        o1 = make_uint4(pw[4],pw[5],pw[6],pw[7]);
      }
      char* dst = ftl + r*FT_STRIDE + q*32;
      *(uint4*)dst = o0;
      *(uint4*)(dst+16) = o1;
    }
  }

  // ---- Phase 2: f_bot in registers, rolled-plane store + g ----
  int lr  = tid >> 4;
  int lc4 = (tid & 15) * 4;
  int trow = itop0 + lr;
  int bq = n >> 4, cq = n & 15;
  int jc = j0 + lc4;

  float vb[3][6];                    // x cols jc-1 .. jc+4
  bool look = (jc >= 4);
  bool hiok = (jc <= 248);
#pragma unroll
  for (int rr=0; rr<3; ++rr){
    int xr = 127 + trow + rr;        // in [127,256]
    bool rok = (xr < 256);
    const float* rp = xp + (size_t)xr*Wd + jc;
    float4 m = rok ? *(const float4*)rp : f4z;
    float lw = (rok && look) ? rp[-1] : 0.f;
    float rw = (rok && hiok) ? rp[4]  : 0.f;
    vb[rr][0]=lw; vb[rr][1]=m.x; vb[rr][2]=m.y; vb[rr][3]=m.z; vb[rr][4]=m.w; vb[rr][5]=rw;
  }
  float fb[4][4];
#pragma unroll
  for (int m=0;m<4;m++)
#pragma unroll
    for (int p=0;p<4;p++){
      float s = b1r[m];
#pragma unroll
      for (int ky=0;ky<3;ky++)
#pragma unroll
        for (int kx=0;kx<3;kx++)
          s = fmaf(vb[ky][p+kx], w1r[m*9+ky*3+kx], s);
      fb[m][p] = mish_s(s);
    }
  int cdst = (cq + 15) & 15;
  size_t bbase = ((size_t)(bq*16 + cdst))*65536 + (size_t)(128+trow)*256 + jc;
  {
    unsigned w0 = packbf(fb[0][0], fb[1][0]), w1 = packbf(fb[2][0], fb[3][0]);
    unsigned w2 = packbf(fb[0][1], fb[1][1]), w3 = packbf(fb[2][1], fb[3][1]);
    *(uint4*)(shuf + bbase*4) = make_uint4(w0,w1,w2,w3);
    unsigned w4 = packbf(fb[0][2], fb[1][2]), w5 = packbf(fb[2][2], fb[3][2]);
    unsigned w6 = packbf(fb[0][3], fb[1][3]), w7 = packbf(fb[2][3], fb[3][3]);
    *(uint4*)(shuf + (bbase+2)*4) = make_uint4(w4,w5,w6,w7);
  }
  float gv[4];
#pragma unroll
  for (int p=0;p<4;p++){
    float s = bredr;
#pragma unroll
    for (int m=0;m<4;m++) s = fmaf(fb[m][p], wredr[m], s);
    gv[p] = fmaxf(s, 0.f);
  }

  __syncthreads();

  // ---- Phase 4: span convs from LDS (slots lc4..lc4+7; used 1..6) ----
  float Aa[4][4], Bb[4][4];
#pragma unroll
  for (int m=0;m<4;m++)
#pragma unroll
    for (int p=0;p<4;p++){ Aa[m][p]=0.f; Bb[m][p]=0.f; }

#pragma unroll
  for (int ky=0;ky<3;ky++){
    const char* src = ftl + (lr+ky)*FT_STRIDE + lc4*8;
    float f0[8], f1[8], f2[8], f3[8];
#pragma unroll
    for (int jj=0;jj<4;jj++){
      uint4 u = *(const uint4*)(src + jj*16);
      f0[2*jj]   = lo16(u.x); f1[2*jj]   = hi16(u.x);
      f2[2*jj]   = lo16(u.y); f3[2*jj]   = hi16(u.y);
      f0[2*jj+1] = lo16(u.z); f1[2*jj+1] = hi16(u.z);
      f2[2*jj+1] = lo16(u.w); f3[2*jj+1] = hi16(u.w);
    }
#pragma unroll
    for (int kx=0;kx<3;kx++){
      float ws = wsp[ky*3+kx], bs = bsp[ky*3+kx];
#pragma unroll
      for (int p=0;p<4;p++){
        int ix = p + 1 + kx;
        Aa[0][p] = fmaf(f0[ix], ws, Aa[0][p]); Bb[0][p] = fmaf(f0[ix], bs, Bb[0][p]);
        Aa[1][p] = fmaf(f1[ix], ws, Aa[1][p]); Bb[1][p] = fmaf(f1[ix], bs, Bb[1][p]);
        Aa[2][p] = fmaf(f2[ix], ws, Aa[2][p]); Bb[2][p] = fmaf(f2[ix], bs, Bb[2][p]);
        Aa[3][p] = fmaf(f3[ix], ws, Aa[3][p]); Bb[3][p] = fmaf(f3[ix], bs, Bb[3][p]);
      }
    }
  }

  float o[4][4];
#pragma unroll
  for (int m=0;m<4;m++)
#pragma unroll
    for (int p=0;p<4;p++)
      o[m][p] = fmaf(gv[p], Aa[m][p], Bb[m][p]);

  size_t pbase = ((size_t)(bq*16 + cq))*65536 + (size_t)trow*256 + jc;
  {
    unsigned w0 = packbf(o[0][0], o[1][0]), w1 = packbf(o[2][0], o[3][0]);
    unsigned w2 = packbf(o[0][1], o[1][1]), w3 = packbf(o[2][1], o[3][1]);
    *(uint4*)(shuf + pbase*4) = make_uint4(w0,w1,w2,w3);
    unsigned w4 = packbf(o[0][2], o[1][2]), w5 = packbf(o[2][2], o[3][2]);
    unsigned w6 = packbf(o[0][3], o[1][3]), w7 = packbf(o[2][3], o[3][3]);
    *(uint4*)(shuf + (pbase+2)*4) = make_uint4(w4,w5,w6,w7);
  }
}

// ---------------------------------------------------------------------------
// K3: conv2 via MFMA implicit GEMM, direct-from-global B fragments.
// ---------------------------------------------------------------------------
__global__ __launch_bounds__(256) void k3_conv2(
    const ushort_t* __restrict__ shuf, const ushort_t* __restrict__ wpack,
    const float* __restrict__ b2, float* __restrict__ scratch)
{
  __shared__ f32x4 mg[2][8][64];   // 16 KiB
  __shared__ float pacc[16];

  int bid0 = blockIdx.x;                     // 2048
  int bid  = (bid0 & 7)*256 + (bid0 >> 3);   // XCD-contiguous chunks
  int b   = bid >> 8;
  int t   = bid & 255;
  int rb  = t >> 3;
  int cb  = t & 7;
  int tid = threadIdx.x;
  int lane = tid & 63;
  int n = lane & 15;
  int g = lane >> 4;
  int wid = tid >> 6;
  int colhalf = wid & 1;
  int khalf   = wid >> 1;

  if (tid < 16) pacc[tid] = 0.f;

  const short8* wp = (const short8*)wpack + (size_t)khalf*576 + lane;
  short8 afr[9];
#pragma unroll
  for (int s = 0; s < 9; ++s) afr[s] = wp[s*64];

  f32x4 acc[8];
#pragma unroll
  for (int r = 0; r < 8; ++r) acc[r] = f32x4{0.f,0.f,0.f,0.f};

  int r0 = rb*8 - 1;
  int c  = cb*32 - 1 + colhalf*16 + n;
  int p0 = khalf*8 + g*2;
  const ushort_t* sp = shuf + ((size_t)(b*16 + p0))*262144;

#pragma unroll
  for (int hr = 0; hr < 10; ++hr){
    int grow = r0 + hr;
    bool rok = (unsigned)grow < 256u;
    uint2 va[3], vb[3];
#pragma unroll
    for (int kx = 0; kx < 3; ++kx){
      int gcol = c + kx;
      uint2 a = make_uint2(0u,0u), bv = make_uint2(0u,0u);
      if (rok && (unsigned)gcol < 256u){
        const ushort_t* pp = sp + (size_t)(grow*256 + gcol)*4;
        a  = *(const uint2*)pp;
        bv = *(const uint2*)(pp + 262144);
      }
      va[kx] = a; vb[kx] = bv;
    }
#pragma unroll
    for (int kx = 0; kx < 3; ++kx){
      union { uint4 u; short8 s; } cv;
      cv.u = make_uint4(va[kx].x, va[kx].y, vb[kx].x, vb[kx].y);
#pragma unroll
      for (int ky = 0; ky < 3; ++ky){
        int orow = hr - ky;
        if (orow >= 0 && orow < 8){
          acc[orow] = __builtin_amdgcn_mfma_f32_16x16x32_bf16(
              afr[ky*3+kx], cv.s, acc[orow], 0, 0, 0);
        }
      }
    }
  }

  if (khalf == 1){
#pragma unroll
    for (int r = 0; r < 8; ++r) mg[colhalf][r][lane] = acc[r];
  }
  __syncthreads();

  if (khalf == 0){
    float b2v[4];
#pragma unroll
    for (int q = 0; q < 4; ++q) b2v[q] = b2[g*4 + q];
    float po[4] = {0.f, 0.f, 0.f, 0.f};
#pragma unroll
    for (int r = 0; r < 8; ++r){
      f32x4 o = acc[r] + mg[colhalf][r][lane];
#pragma unroll
      for (int q = 0; q < 4; ++q) po[q] += mishf(o[q] + b2v[q]);
    }
#pragma unroll
    for (int q = 0; q < 4; ++q){
#pragma unroll
      for (int mk = 1; mk < 16; mk <<= 1) po[q] += __shfl_xor(po[q], mk);
    }
    if (n == 0){
#pragma unroll
      for (int q = 0; q < 4; ++q) atomicAdd(&pacc[g*4 + q], po[q]);
    }
  }
  __syncthreads();
  if (tid < 16) scratch[bid*16 + tid] = pacc[tid];
}

// K4: reduce per-block partials -> pooled mean -> ECA gate. One block per b.
__global__ void k4_gate(const float* __restrict__ scratch,
                        const float* __restrict__ Weca,
                        float* __restrict__ gate)
{
  __shared__ float rr[16][16];
  __shared__ float pool[16];
  int b = blockIdx.x;
  int t = threadIdx.x;           // 256
  int oc = t & 15, ch = t >> 4;
  float s = 0.f;
  for (int u = 0; u < 16; ++u)
    s += scratch[(size_t)(b*256 + ch*16 + u)*16 + oc];
  rr[ch][oc] = s;
  __syncthreads();
  if (t < 16){
    float tot = 0.f;
#pragma unroll
    for (int k = 0; k < 16; ++k) tot += rr[k][t];
    pool[t] = tot * (1.0f/65536.0f);
  }
  __syncthreads();
  if (t < 16){
    float pm = (t > 0)  ? pool[t-1] : 0.f;
    float p0 = pool[t];
    float pp = (t < 15) ? pool[t+1] : 0.f;
    float z = Weca[0]*pm + Weca[1]*p0 + Weca[2]*pp;
    gate[b*16 + t] = 1.f/(1.f + __expf(-z));
  }
}

// K5: out = x * gate[b,c], nontemporal stores
__global__ __launch_bounds__(256) void k5_scale(
    const f32x4* __restrict__ x4, const float* __restrict__ gate,
    f32x4* __restrict__ out4)
{
  int idx = blockIdx.x*256 + threadIdx.x;
  float g = gate[idx >> 14];
  f32x4 v = x4[idx] * g;
  __builtin_nontemporal_store(v, &out4[idx]);
}

extern "C" void kernel_launch(void* const* d_in, const int* in_sizes, int n_in,
                              void* d_out, int out_size, void* d_ws, size_t ws_size,
                              hipStream_t stream)
{
  const float* x     = (const float*)d_in[0];
  const float* W1    = (const float*)d_in[1];
  const float* b1    = (const float*)d_in[2];
  const float* Wred  = (const float*)d_in[3];
  const float* bred  = (const float*)d_in[4];
  const float* Wspan = (const float*)d_in[5];
  const float* bspan = (const float*)d_in[6];
  const float* W2    = (const float*)d_in[7];
  const float* b2    = (const float*)d_in[8];
  const float* Weca  = (const float*)d_in[9];

  ushort_t* shuf    = (ushort_t*)d_ws;                        // 64 MiB records
  float*    gate    = (float*)((char*)d_ws + 67108864);       // 512 B
  ushort_t* wpack   = (ushort_t*)((char*)d_ws + 67108864 + 1024); // 18.4 KiB
  float*    scratch = (float*)d_out;  // 2048*16 floats; overwritten by k5

  k0_pack<<<9, 128, 0, stream>>>(W2, wpack);
  k12h   <<<4096, 256, 0, stream>>>(x, W1, b1, Wred, bred, Wspan, bspan, shuf);
  k3_conv2<<<2048, 256, 0, stream>>>(shuf, wpack, b2, scratch);
  k4_gate<<<8, 256, 0, stream>>>(scratch, Weca, gate);
  k5_scale<<<8192, 256, 0, stream>>>((const f32x4*)x, gate, (f32x4*)d_out);
}